// Round 15
// baseline (2817.512 us; speedup 1.0000x reference)
//
#include <hip/hip_runtime.h>
#include <hip/hip_fp16.h>

// Persistent 2D-LSTM, self-validating tagged-ring protocol (no fences/flags).
// B=64, NC=512, T=1024, K=1216 = [x 0..191 | h(t-32) 192..703 | h(t-1) 704..1215].
// 4 batch-groups x 64 col-WGs = 256 WGs x 512 thr (1 WG/CU, 112KB LDS).
// WG (g,w): batches g*16..+15, channels w*8..+7 (x4 gates = 32 gate-cols).
// Ring FRAGMENT-MAJOR (r14): per (slot,g) block of 2048 u64,
//   u64 idx = chunk*128 + 2*lane (+0/+1) -> wave reads 1KB contiguous.
// Tags: each fp16 LSB = generation parity ((t>>6)&1); pre-memset 0x01.
// r15: round-0 consume loads are NORMAL CACHEABLE loads (coalesce + L2-share
// across the ~8 WGs/XCD of a group); retry rounds use agent-scope atomic
// loads (L2-bypass, fresh) so stale L2 hits are bounded by one retry RTT.

typedef __attribute__((ext_vector_type(8))) _Float16 half8;
typedef __attribute__((ext_vector_type(4))) float f32x4;
typedef unsigned long long u64;

#define T_ 1024

#define LDS_W    77824              // 38 chunks * 2 tiles * 64 lanes * 16B
#define LDS_PSM  33792              // f32 [2][8][16][33]
#define LDS_ALL  (LDS_W + LDS_PSM + 512)

extern __shared__ char smem[];

__global__ __launch_bounds__(512, 1) void lstm_persist(
    const float* __restrict__ x, const float* __restrict__ Wih,
    const float* __restrict__ Whh, const float* __restrict__ bih,
    const float* __restrict__ bhh, float* __restrict__ out,
    u64* ring)
{
    _Float16* Wsm = (_Float16*)smem;
    float*    Psm = (float*)(smem + LDS_W);
    float*    cst = (float*)(smem + LDS_W + LDS_PSM);

    const int tid = threadIdx.x;
    const int l   = tid & 63, wv = tid >> 6;
    const int l15 = l & 15,  l4 = l >> 4;
    const int bid = blockIdx.x;
    const int g   = bid >> 6;          // batch group 0..3
    const int w   = bid & 63;          // channel WG 0..63

    // ---- weights fp32 -> fp16 fragments in LDS (once) ----
    // tile col co = nb*16 + l15: gate = l15&3, ch_local = nb*4 + (l15>>2)
    for (int p = wv; p < 76; p += 8) {
        const int c = p >> 1, nb = p & 1;
        const int rj = (l15 & 3) * 512 + w * 8 + nb * 4 + (l15 >> 2);
        const int k  = c * 32 + l4 * 8;
        const float* src = (c < 22) ? (Wih + (size_t)rj * 704 + k)
                                    : (Whh + (size_t)rj * 512 + (k - 704));
        float4 v0 = ((const float4*)src)[0];
        float4 v1 = ((const float4*)src)[1];
        half8 hb;
        hb[0]=(_Float16)v0.x; hb[1]=(_Float16)v0.y; hb[2]=(_Float16)v0.z; hb[3]=(_Float16)v0.w;
        hb[4]=(_Float16)v1.x; hb[5]=(_Float16)v1.y; hb[6]=(_Float16)v1.z; hb[7]=(_Float16)v1.w;
        *(half8*)(Wsm + (size_t)((c * 2 + nb) * 64 + l) * 8) = hb;
    }
    if (tid < 128) cst[tid] = 0.f;

    // pointwise role (tid<128): pb = batch 0..15, pc = channel 0..7
    const int pb = tid >> 3, pc = tid & 7;
    const int gc = w * 8 + pc;
    const float bI = bih[gc]        + bhh[gc];
    const float bF = bih[512 + gc]  + bhh[512 + gc];
    const float bG = bih[1024 + gc] + bhh[1024 + gc];
    const float bO = bih[1536 + gc] + bhh[1536 + gc];
    __syncthreads();

    // per-wave chunk ownership: all c in 0..37 with c%8 == wv
    const int coff = (wv + 2) & 7;
    const int c32a = 6 + coff,  c32b = 14 + coff;   // h(t-32) chunks
    const int c1a  = 22 + coff, c1b  = 30 + coff;   // h(t-1) chunks
    const int gb   = g * 16 + l15;                  // A-row batch

    auto wfrag = [&](int c, int nb) -> half8 {
        return *(const half8*)(Wsm + (size_t)((c * 2 + nb) * 64 + l) * 8);
    };
    // tagged ring fragment load, fragment-major layout.
    // Round 0: normal cacheable load (coalesced, L2-shareable).
    // Retries: agent-scope atomic load (L2-bypass -> always fresh).
    auto loadfrag = [&](int slot, int cc, unsigned par_) -> half8 {
        const size_t idx = ((size_t)(slot * 4 + g)) * 2048 + (size_t)cc * 128 + 2 * l;
        const u64 M  = 0x0001000100010001ULL;
        const u64 ex = par_ ? M : 0ULL;
        const volatile u64* rp = (const volatile u64*)(ring + idx);
        u64 v0 = rp[0];
        u64 v1 = rp[1];
        bool ok = ((v0 & M) == ex) && ((v1 & M) == ex);
        while (!__all(ok)) {
            __builtin_amdgcn_s_sleep(1);   // space out retry rounds
            if (!ok) {
                v0 = __hip_atomic_load(ring + idx,     __ATOMIC_RELAXED, __HIP_MEMORY_SCOPE_AGENT);
                v1 = __hip_atomic_load(ring + idx + 1, __ATOMIC_RELAXED, __HIP_MEMORY_SCOPE_AGENT);
                ok = ((v0 & M) == ex) && ((v1 & M) == ex);
            }
        }
        union { u64 u[2]; half8 h; } cc_;
        cc_.u[0] = v0; cc_.u[1] = v1;
        return cc_.h;
    };

    float4 xa0, xa1;
    half8  h32a, h32b;
    if (wv < 6) {   // x prefetch for t=0 (y=0, xc=0)
        const int k0 = wv * 32 + l4 * 8;
        const float* xs = x + ((size_t)(gb * 3 + (k0 >> 6)) * 256 + ((k0 >> 3) & 7)) * 256;
        xa0 = ((const float4*)xs)[0];
        xa1 = ((const float4*)xs)[1];
    }

    for (int t = 0; t < T_; ++t) {
        const int par = t & 1;
        f32x4 acc0 = {0.f,0.f,0.f,0.f}, acc1 = {0.f,0.f,0.f,0.f};

        // [A] x part (prefetched regs)
        if (wv < 6) {
            half8 a;
            a[0]=(_Float16)xa0.x; a[1]=(_Float16)xa0.y; a[2]=(_Float16)xa0.z; a[3]=(_Float16)xa0.w;
            a[4]=(_Float16)xa1.x; a[5]=(_Float16)xa1.y; a[6]=(_Float16)xa1.z; a[7]=(_Float16)xa1.w;
            acc0 = __builtin_amdgcn_mfma_f32_16x16x32_f16(a, wfrag(wv,0), acc0, 0,0,0);
            acc1 = __builtin_amdgcn_mfma_f32_16x16x32_f16(a, wfrag(wv,1), acc1, 0,0,0);
        }
        // [B] h(t-32) part (prefetched regs)
        if (t >= 32) {
            acc0 = __builtin_amdgcn_mfma_f32_16x16x32_f16(h32a, wfrag(c32a,0), acc0, 0,0,0);
            acc1 = __builtin_amdgcn_mfma_f32_16x16x32_f16(h32a, wfrag(c32a,1), acc1, 0,0,0);
            acc0 = __builtin_amdgcn_mfma_f32_16x16x32_f16(h32b, wfrag(c32b,0), acc0, 0,0,0);
            acc1 = __builtin_amdgcn_mfma_f32_16x16x32_f16(h32b, wfrag(c32b,1), acc1, 0,0,0);
        }
        // [C] h(t-1): tagged wait + MFMA (the only real stall)
        if (t > 0) {
            const int sP = (t - 1) & 63;
            const unsigned p1 = ((t - 1) >> 6) & 1;
            half8 ha = loadfrag(sP, c1a - 22, p1);
            acc0 = __builtin_amdgcn_mfma_f32_16x16x32_f16(ha, wfrag(c1a,0), acc0, 0,0,0);
            acc1 = __builtin_amdgcn_mfma_f32_16x16x32_f16(ha, wfrag(c1a,1), acc1, 0,0,0);
            half8 hb = loadfrag(sP, c1b - 22, p1);
            acc0 = __builtin_amdgcn_mfma_f32_16x16x32_f16(hb, wfrag(c1b,0), acc0, 0,0,0);
            acc1 = __builtin_amdgcn_mfma_f32_16x16x32_f16(hb, wfrag(c1b,1), acc1, 0,0,0);
        }

        // [D] partials -> LDS (parity double-buffer)
        {
            float* Pw = Psm + (size_t)((par * 8 + wv) * 16) * 33;
#pragma unroll
            for (int r = 0; r < 4; ++r) {
                Pw[(l4 * 4 + r) * 33 + l15]      = acc0[r];
                Pw[(l4 * 4 + r) * 33 + 16 + l15] = acc1[r];
            }
        }
        __syncthreads();   // [E] the only barrier per step

        // [F] pointwise + tagged publish (waves 0-1); waves 2-7 run ahead
        if (tid < 128) {
            float gi = bI, gf = bF, gg = bG, go = bO;
#pragma unroll
            for (int q = 0; q < 8; ++q) {
                const float* Pq = Psm + ((size_t)((par * 8 + q) * 16 + pb)) * 33 + pc * 4;
                gi += Pq[0]; gf += Pq[1]; gg += Pq[2]; go += Pq[3];
            }
            const float cprev = cst[tid];
            const float si = 1.f / (1.f + __expf(-gi));
            const float sf = 1.f / (1.f + __expf(-gf));
            const float so = 1.f / (1.f + __expf(-go));
            const float tg = 2.f / (1.f + __expf(-2.f * gg)) - 1.f;
            const float cn = sf * cprev + si * tg;
            const float th = 2.f / (1.f + __expf(-2.f * cn)) - 1.f;
            const float hn = so * th;
            cst[tid] = cn;

            union { _Float16 f; unsigned short s; } cv; cv.f = (_Float16)hn;
            unsigned hb16 = ((unsigned)cv.s & ~1u) | (unsigned)((t >> 6) & 1);  // force tag
            unsigned other = (unsigned)__shfl_xor((int)hb16, 1);
            unsigned pairv = (pc & 1) ? ((other & 0xffffu) | (hb16 << 16))
                                      : ((hb16 & 0xffffu) | (other << 16));
            unsigned hi = (unsigned)__shfl_xor((int)pairv, 2);
            if ((pc & 3) == 0) {
                u64 val = (u64)pairv | ((u64)hi << 32);
                // fragment-major publish: u64 idx = block + w*32 + pb*2 + (pc>>2)
                const size_t idx = ((size_t)((t & 63) * 4 + g)) * 2048
                                 + (size_t)w * 32 + (size_t)pb * 2 + (pc >> 2);
                __hip_atomic_store(ring + idx, val, __ATOMIC_RELAXED,
                                   __HIP_MEMORY_SCOPE_AGENT);
            }
            out[(size_t)(g * 16 + pb) * (T_ * 512) + (size_t)t * 512 + gc] = hn;
        }

        // [G/H] prefetch next step: x and h(t+1-32) (31-step-old => no stall)
        const int tn = t + 1;
        if (tn < T_) {
            if (wv < 6) {
                const int yn = tn >> 5, xcn = tn & 31;
                const int k0 = wv * 32 + l4 * 8;
                const float* xs = x + ((size_t)(gb * 3 + (k0 >> 6)) * 256
                                       + yn * 8 + ((k0 >> 3) & 7)) * 256 + xcn * 8;
                xa0 = ((const float4*)xs)[0];
                xa1 = ((const float4*)xs)[1];
            }
            if (tn >= 32) {
                const int sO = (tn - 32) & 63;
                const unsigned p32 = ((tn - 32) >> 6) & 1;
                h32a = loadfrag(sO, c32a - 6, p32);
                h32b = loadfrag(sO, c32b - 6, p32);
            }
        }
    }
}

extern "C" void kernel_launch(void* const* d_in, const int* in_sizes, int n_in,
                              void* d_out, int out_size, void* d_ws, size_t ws_size,
                              hipStream_t stream) {
    const float* x   = (const float*)d_in[0];
    const float* Wih = (const float*)d_in[1];
    const float* Whh = (const float*)d_in[2];
    const float* bih = (const float*)d_in[3];
    const float* bhh = (const float*)d_in[4];
    float* out = (float*)d_out;

    u64* ring = (u64*)d_ws;   // 64*4*2048 u64 = 4 MB

    // LSB pattern 1 everywhere != gen-0 parity 0
    hipMemsetAsync(ring, 0x01, 64ull * 4 * 2048 * 8, stream);

    (void)hipFuncSetAttribute((const void*)lstm_persist,
                              hipFuncAttributeMaxDynamicSharedMemorySize, LDS_ALL);

    hipLaunchKernelGGL(lstm_persist, dim3(256), dim3(512), LDS_ALL, stream,
                       x, Wih, Whh, bih, bhh, out, ring);
}

// Round 16
// 2657.527 us; speedup vs baseline: 1.0602x; 1.0602x over previous
//
#include <hip/hip_runtime.h>
#include <hip/hip_fp16.h>

// Persistent 2D-LSTM, self-validating tagged-ring protocol (no fences/flags).
// B=64, NC=512, T=1024, K=1216 = [x 0..191 | h(t-32) 192..703 | h(t-1) 704..1215].
// 4 batch-groups x 64 col-WGs = 256 WGs x 512 thr (1 WG/CU, 112KB LDS).
// WG (g,w): batches g*16..+15, channels w*8..+7 (x4 gates = 32 gate-cols).
// Ring FRAGMENT-MAJOR (r14): per (slot,g) block of 2048 u64,
//   u64 idx = chunk*128 + 2*lane (+0/+1) -> wave reads 1KB contiguous.
// Tags: each fp16 LSB = generation parity ((t>>6)&1); pre-memset 0x01.
// Consume loads: agent-scope atomics ONLY (r15 showed cacheable round-0 hits
// stale L2 -> forced retries; MALL-direct is strictly better here).
// r16: dual-chunk fused loads -- both chunks' 4 u64 issued together, one
// validate loop. [G/H] and [C] each collapse 2 serial RTTs -> 1.

typedef __attribute__((ext_vector_type(8))) _Float16 half8;
typedef __attribute__((ext_vector_type(4))) float f32x4;
typedef unsigned long long u64;

#define T_ 1024

#define LDS_W    77824              // 38 chunks * 2 tiles * 64 lanes * 16B
#define LDS_PSM  33792              // f32 [2][8][16][33]
#define LDS_ALL  (LDS_W + LDS_PSM + 512)

extern __shared__ char smem[];

__global__ __launch_bounds__(512, 1) void lstm_persist(
    const float* __restrict__ x, const float* __restrict__ Wih,
    const float* __restrict__ Whh, const float* __restrict__ bih,
    const float* __restrict__ bhh, float* __restrict__ out,
    u64* ring)
{
    _Float16* Wsm = (_Float16*)smem;
    float*    Psm = (float*)(smem + LDS_W);
    float*    cst = (float*)(smem + LDS_W + LDS_PSM);

    const int tid = threadIdx.x;
    const int l   = tid & 63, wv = tid >> 6;
    const int l15 = l & 15,  l4 = l >> 4;
    const int bid = blockIdx.x;
    const int g   = bid >> 6;          // batch group 0..3
    const int w   = bid & 63;          // channel WG 0..63

    // ---- weights fp32 -> fp16 fragments in LDS (once) ----
    // tile col co = nb*16 + l15: gate = l15&3, ch_local = nb*4 + (l15>>2)
    for (int p = wv; p < 76; p += 8) {
        const int c = p >> 1, nb = p & 1;
        const int rj = (l15 & 3) * 512 + w * 8 + nb * 4 + (l15 >> 2);
        const int k  = c * 32 + l4 * 8;
        const float* src = (c < 22) ? (Wih + (size_t)rj * 704 + k)
                                    : (Whh + (size_t)rj * 512 + (k - 704));
        float4 v0 = ((const float4*)src)[0];
        float4 v1 = ((const float4*)src)[1];
        half8 hb;
        hb[0]=(_Float16)v0.x; hb[1]=(_Float16)v0.y; hb[2]=(_Float16)v0.z; hb[3]=(_Float16)v0.w;
        hb[4]=(_Float16)v1.x; hb[5]=(_Float16)v1.y; hb[6]=(_Float16)v1.z; hb[7]=(_Float16)v1.w;
        *(half8*)(Wsm + (size_t)((c * 2 + nb) * 64 + l) * 8) = hb;
    }
    if (tid < 128) cst[tid] = 0.f;

    // pointwise role (tid<128): pb = batch 0..15, pc = channel 0..7
    const int pb = tid >> 3, pc = tid & 7;
    const int gc = w * 8 + pc;
    const float bI = bih[gc]        + bhh[gc];
    const float bF = bih[512 + gc]  + bhh[512 + gc];
    const float bG = bih[1024 + gc] + bhh[1024 + gc];
    const float bO = bih[1536 + gc] + bhh[1536 + gc];
    __syncthreads();

    // per-wave chunk ownership: all c in 0..37 with c%8 == wv
    const int coff = (wv + 2) & 7;
    const int c32a = 6 + coff,  c32b = 14 + coff;   // h(t-32) chunks
    const int c1a  = 22 + coff, c1b  = 30 + coff;   // h(t-1) chunks
    const int gb   = g * 16 + l15;                  // A-row batch

    auto wfrag = [&](int c, int nb) -> half8 {
        return *(const half8*)(Wsm + (size_t)((c * 2 + nb) * 64 + l) * 8);
    };
    auto rld = [&](size_t i) -> u64 {
        return __hip_atomic_load(ring + i, __ATOMIC_RELAXED, __HIP_MEMORY_SCOPE_AGENT);
    };
    // r16: fused dual-chunk tagged load -- 4 u64 issued together, one validate
    // loop (one RTT instead of two serial). Retries sleep-spaced.
    auto loadfrag2x = [&](int slot, int cc0, int cc1, unsigned par_,
                          half8& h0, half8& h1) {
        const size_t blk = ((size_t)(slot * 4 + g)) * 2048 + 2 * l;
        const size_t i0 = blk + (size_t)cc0 * 128;
        const size_t i1 = blk + (size_t)cc1 * 128;
        const u64 M  = 0x0001000100010001ULL;
        const u64 ex = par_ ? M : 0ULL;
        u64 a0 = rld(i0), a1 = rld(i0 + 1);
        u64 b0 = rld(i1), b1 = rld(i1 + 1);
        bool ok = ((a0 & M) == ex) && ((a1 & M) == ex) &&
                  ((b0 & M) == ex) && ((b1 & M) == ex);
        while (!__all(ok)) {
            __builtin_amdgcn_s_sleep(1);
            if (!ok) {
                a0 = rld(i0); a1 = rld(i0 + 1);
                b0 = rld(i1); b1 = rld(i1 + 1);
                ok = ((a0 & M) == ex) && ((a1 & M) == ex) &&
                     ((b0 & M) == ex) && ((b1 & M) == ex);
            }
        }
        union { u64 u[2]; half8 h; } ca, cb;
        ca.u[0] = a0; ca.u[1] = a1; cb.u[0] = b0; cb.u[1] = b1;
        h0 = ca.h; h1 = cb.h;
    };

    float4 xa0, xa1;
    half8  h32a, h32b;
    if (wv < 6) {   // x prefetch for t=0 (y=0, xc=0)
        const int k0 = wv * 32 + l4 * 8;
        const float* xs = x + ((size_t)(gb * 3 + (k0 >> 6)) * 256 + ((k0 >> 3) & 7)) * 256;
        xa0 = ((const float4*)xs)[0];
        xa1 = ((const float4*)xs)[1];
    }

    for (int t = 0; t < T_; ++t) {
        const int par = t & 1;
        f32x4 acc0 = {0.f,0.f,0.f,0.f}, acc1 = {0.f,0.f,0.f,0.f};

        // [A] x part (prefetched regs)
        if (wv < 6) {
            half8 a;
            a[0]=(_Float16)xa0.x; a[1]=(_Float16)xa0.y; a[2]=(_Float16)xa0.z; a[3]=(_Float16)xa0.w;
            a[4]=(_Float16)xa1.x; a[5]=(_Float16)xa1.y; a[6]=(_Float16)xa1.z; a[7]=(_Float16)xa1.w;
            acc0 = __builtin_amdgcn_mfma_f32_16x16x32_f16(a, wfrag(wv,0), acc0, 0,0,0);
            acc1 = __builtin_amdgcn_mfma_f32_16x16x32_f16(a, wfrag(wv,1), acc1, 0,0,0);
        }
        // [B] h(t-32) part (prefetched regs)
        if (t >= 32) {
            acc0 = __builtin_amdgcn_mfma_f32_16x16x32_f16(h32a, wfrag(c32a,0), acc0, 0,0,0);
            acc1 = __builtin_amdgcn_mfma_f32_16x16x32_f16(h32a, wfrag(c32a,1), acc1, 0,0,0);
            acc0 = __builtin_amdgcn_mfma_f32_16x16x32_f16(h32b, wfrag(c32b,0), acc0, 0,0,0);
            acc1 = __builtin_amdgcn_mfma_f32_16x16x32_f16(h32b, wfrag(c32b,1), acc1, 0,0,0);
        }
        // [C] h(t-1): fused dual-chunk tagged wait + 4 MFMAs (one RTT)
        if (t > 0) {
            const int sP = (t - 1) & 63;
            const unsigned p1 = ((t - 1) >> 6) & 1;
            half8 ha, hb;
            loadfrag2x(sP, c1a - 22, c1b - 22, p1, ha, hb);
            acc0 = __builtin_amdgcn_mfma_f32_16x16x32_f16(ha, wfrag(c1a,0), acc0, 0,0,0);
            acc1 = __builtin_amdgcn_mfma_f32_16x16x32_f16(ha, wfrag(c1a,1), acc1, 0,0,0);
            acc0 = __builtin_amdgcn_mfma_f32_16x16x32_f16(hb, wfrag(c1b,0), acc0, 0,0,0);
            acc1 = __builtin_amdgcn_mfma_f32_16x16x32_f16(hb, wfrag(c1b,1), acc1, 0,0,0);
        }

        // [D] partials -> LDS (parity double-buffer)
        {
            float* Pw = Psm + (size_t)((par * 8 + wv) * 16) * 33;
#pragma unroll
            for (int r = 0; r < 4; ++r) {
                Pw[(l4 * 4 + r) * 33 + l15]      = acc0[r];
                Pw[(l4 * 4 + r) * 33 + 16 + l15] = acc1[r];
            }
        }
        __syncthreads();   // [E] the only barrier per step

        // [F] pointwise + tagged publish (waves 0-1); waves 2-7 run ahead
        if (tid < 128) {
            float gi = bI, gf = bF, gg = bG, go = bO;
#pragma unroll
            for (int q = 0; q < 8; ++q) {
                const float* Pq = Psm + ((size_t)((par * 8 + q) * 16 + pb)) * 33 + pc * 4;
                gi += Pq[0]; gf += Pq[1]; gg += Pq[2]; go += Pq[3];
            }
            const float cprev = cst[tid];
            const float si = 1.f / (1.f + __expf(-gi));
            const float sf = 1.f / (1.f + __expf(-gf));
            const float so = 1.f / (1.f + __expf(-go));
            const float tg = 2.f / (1.f + __expf(-2.f * gg)) - 1.f;
            const float cn = sf * cprev + si * tg;
            const float th = 2.f / (1.f + __expf(-2.f * cn)) - 1.f;
            const float hn = so * th;
            cst[tid] = cn;

            union { _Float16 f; unsigned short s; } cv; cv.f = (_Float16)hn;
            unsigned hb16 = ((unsigned)cv.s & ~1u) | (unsigned)((t >> 6) & 1);  // force tag
            unsigned other = (unsigned)__shfl_xor((int)hb16, 1);
            unsigned pairv = (pc & 1) ? ((other & 0xffffu) | (hb16 << 16))
                                      : ((hb16 & 0xffffu) | (other << 16));
            unsigned hi = (unsigned)__shfl_xor((int)pairv, 2);
            if ((pc & 3) == 0) {
                u64 val = (u64)pairv | ((u64)hi << 32);
                // fragment-major publish: u64 idx = block + w*32 + pb*2 + (pc>>2)
                const size_t idx = ((size_t)((t & 63) * 4 + g)) * 2048
                                 + (size_t)w * 32 + (size_t)pb * 2 + (pc >> 2);
                __hip_atomic_store(ring + idx, val, __ATOMIC_RELAXED,
                                   __HIP_MEMORY_SCOPE_AGENT);
            }
            out[(size_t)(g * 16 + pb) * (T_ * 512) + (size_t)t * 512 + gc] = hn;
        }

        // [G/H] prefetch next step: x and h(t+1-32) fused (one RTT, always ready)
        const int tn = t + 1;
        if (tn < T_) {
            if (wv < 6) {
                const int yn = tn >> 5, xcn = tn & 31;
                const int k0 = wv * 32 + l4 * 8;
                const float* xs = x + ((size_t)(gb * 3 + (k0 >> 6)) * 256
                                       + yn * 8 + ((k0 >> 3) & 7)) * 256 + xcn * 8;
                xa0 = ((const float4*)xs)[0];
                xa1 = ((const float4*)xs)[1];
            }
            if (tn >= 32) {
                const int sO = (tn - 32) & 63;
                const unsigned p32 = ((tn - 32) >> 6) & 1;
                loadfrag2x(sO, c32a - 6, c32b - 6, p32, h32a, h32b);
            }
        }
    }
}

extern "C" void kernel_launch(void* const* d_in, const int* in_sizes, int n_in,
                              void* d_out, int out_size, void* d_ws, size_t ws_size,
                              hipStream_t stream) {
    const float* x   = (const float*)d_in[0];
    const float* Wih = (const float*)d_in[1];
    const float* Whh = (const float*)d_in[2];
    const float* bih = (const float*)d_in[3];
    const float* bhh = (const float*)d_in[4];
    float* out = (float*)d_out;

    u64* ring = (u64*)d_ws;   // 64*4*2048 u64 = 4 MB

    // LSB pattern 1 everywhere != gen-0 parity 0
    hipMemsetAsync(ring, 0x01, 64ull * 4 * 2048 * 8, stream);

    (void)hipFuncSetAttribute((const void*)lstm_persist,
                              hipFuncAttributeMaxDynamicSharedMemorySize, LDS_ALL);

    hipLaunchKernelGGL(lstm_persist, dim3(256), dim3(512), LDS_ALL, stream,
                       x, Wih, Whh, bih, bhh, out, ring);
}

// Round 17
// 2461.772 us; speedup vs baseline: 1.1445x; 1.0795x over previous
//
#include <hip/hip_runtime.h>
#include <hip/hip_fp16.h>

// Persistent 2D-LSTM, self-validating tagged-ring protocol (no fences/flags).
// B=64, NC=512, T=1024, K=1216 = [x 0..191 | h(t-32) 192..703 | h(t-1) 704..1215].
// 4 batch-groups x 64 col-WGs = 256 WGs x 512 thr (1 WG/CU, 112KB LDS).
// WG (g,w): batches g*16..+15, channels w*8..+7 (x4 gates = 32 gate-cols).
// Ring FRAGMENT-MAJOR (r14): per (slot,g) block of 2048 u64,
//   u64 idx = chunk*128 + 2*lane (+0/+1) -> wave reads 1KB contiguous.
// Tags: each fp16 LSB = generation parity ((t>>6)&1); pre-memset 0x01.
// r17: MALL op-count halved -- consume = one global_load_dwordx4 sc0 sc1 per
// chunk (16B, MALL-direct like agent atomics; L2 bypass per r15 lesson);
// publish = one global_store_dwordx4 sc0 sc1 per 4-channel pair-row (16B).

typedef __attribute__((ext_vector_type(8))) _Float16 half8;
typedef __attribute__((ext_vector_type(4))) float f32x4;
typedef __attribute__((ext_vector_type(4))) unsigned u32x4;
typedef unsigned long long u64;

#define T_ 1024

#define LDS_W    77824              // 38 chunks * 2 tiles * 64 lanes * 16B
#define LDS_PSM  33792              // f32 [2][8][16][33]
#define LDS_ALL  (LDS_W + LDS_PSM + 512)

extern __shared__ char smem[];

__global__ __launch_bounds__(512, 1) void lstm_persist(
    const float* __restrict__ x, const float* __restrict__ Wih,
    const float* __restrict__ Whh, const float* __restrict__ bih,
    const float* __restrict__ bhh, float* __restrict__ out,
    u64* ring)
{
    _Float16* Wsm = (_Float16*)smem;
    float*    Psm = (float*)(smem + LDS_W);
    float*    cst = (float*)(smem + LDS_W + LDS_PSM);

    const int tid = threadIdx.x;
    const int l   = tid & 63, wv = tid >> 6;
    const int l15 = l & 15,  l4 = l >> 4;
    const int bid = blockIdx.x;
    const int g   = bid >> 6;          // batch group 0..3
    const int w   = bid & 63;          // channel WG 0..63

    // ---- weights fp32 -> fp16 fragments in LDS (once) ----
    // tile col co = nb*16 + l15: gate = l15&3, ch_local = nb*4 + (l15>>2)
    for (int p = wv; p < 76; p += 8) {
        const int c = p >> 1, nb = p & 1;
        const int rj = (l15 & 3) * 512 + w * 8 + nb * 4 + (l15 >> 2);
        const int k  = c * 32 + l4 * 8;
        const float* src = (c < 22) ? (Wih + (size_t)rj * 704 + k)
                                    : (Whh + (size_t)rj * 512 + (k - 704));
        float4 v0 = ((const float4*)src)[0];
        float4 v1 = ((const float4*)src)[1];
        half8 hb;
        hb[0]=(_Float16)v0.x; hb[1]=(_Float16)v0.y; hb[2]=(_Float16)v0.z; hb[3]=(_Float16)v0.w;
        hb[4]=(_Float16)v1.x; hb[5]=(_Float16)v1.y; hb[6]=(_Float16)v1.z; hb[7]=(_Float16)v1.w;
        *(half8*)(Wsm + (size_t)((c * 2 + nb) * 64 + l) * 8) = hb;
    }
    if (tid < 128) cst[tid] = 0.f;

    // pointwise role (tid<128): pb = batch 0..15, pc = channel 0..7
    const int pb = tid >> 3, pc = tid & 7;
    const int gc = w * 8 + pc;
    const float bI = bih[gc]        + bhh[gc];
    const float bF = bih[512 + gc]  + bhh[512 + gc];
    const float bG = bih[1024 + gc] + bhh[1024 + gc];
    const float bO = bih[1536 + gc] + bhh[1536 + gc];
    __syncthreads();

    // per-wave chunk ownership: all c in 0..37 with c%8 == wv
    const int coff = (wv + 2) & 7;
    const int c32a = 6 + coff,  c32b = 14 + coff;   // h(t-32) chunks
    const int c1a  = 22 + coff, c1b  = 30 + coff;   // h(t-1) chunks
    const int gb   = g * 16 + l15;                  // A-row batch

    auto wfrag = [&](int c, int nb) -> half8 {
        return *(const half8*)(Wsm + (size_t)((c * 2 + nb) * 64 + l) * 8);
    };
    // dual 16B MALL-direct loads (one vmem op per chunk), single drain
    auto ld2 = [&](const u64* pa, const u64* pb, u32x4& ra, u32x4& rb) {
        asm volatile(
            "global_load_dwordx4 %0, %2, off sc0 sc1\n\t"
            "global_load_dwordx4 %1, %3, off sc0 sc1\n\t"
            "s_waitcnt vmcnt(0)"
            : "=&v"(ra), "=&v"(rb)
            : "v"(pa), "v"(pb)
            : "memory");
    };
    auto tagok = [&](u32x4 r, unsigned ex) -> bool {
        const unsigned m = 0x00010001u;
        return ((r[0] & m) == ex) && ((r[1] & m) == ex) &&
               ((r[2] & m) == ex) && ((r[3] & m) == ex);
    };
    // fused dual-chunk tagged load: both chunks issued together, one validate
    auto loadfrag2x = [&](int slot, int cc0, int cc1, unsigned par_,
                          half8& h0, half8& h1) {
        const size_t blk = ((size_t)(slot * 4 + g)) * 2048 + 2 * l;
        const u64* pa = ring + blk + (size_t)cc0 * 128;
        const u64* pb = ring + blk + (size_t)cc1 * 128;
        const unsigned ex = par_ ? 0x00010001u : 0u;
        u32x4 ra, rb;
        ld2(pa, pb, ra, rb);
        bool ok = tagok(ra, ex) && tagok(rb, ex);
        while (!__all(ok)) {
            __builtin_amdgcn_s_sleep(1);
            if (!ok) {
                ld2(pa, pb, ra, rb);
                ok = tagok(ra, ex) && tagok(rb, ex);
            }
        }
        union { u32x4 v; half8 h; } ca, cb;
        ca.v = ra; cb.v = rb;
        h0 = ca.h; h1 = cb.h;
    };

    float4 xa0, xa1;
    half8  h32a, h32b;
    if (wv < 6) {   // x prefetch for t=0 (y=0, xc=0)
        const int k0 = wv * 32 + l4 * 8;
        const float* xs = x + ((size_t)(gb * 3 + (k0 >> 6)) * 256 + ((k0 >> 3) & 7)) * 256;
        xa0 = ((const float4*)xs)[0];
        xa1 = ((const float4*)xs)[1];
    }

    for (int t = 0; t < T_; ++t) {
        const int par = t & 1;
        f32x4 acc0 = {0.f,0.f,0.f,0.f}, acc1 = {0.f,0.f,0.f,0.f};

        // [A] x part (prefetched regs)
        if (wv < 6) {
            half8 a;
            a[0]=(_Float16)xa0.x; a[1]=(_Float16)xa0.y; a[2]=(_Float16)xa0.z; a[3]=(_Float16)xa0.w;
            a[4]=(_Float16)xa1.x; a[5]=(_Float16)xa1.y; a[6]=(_Float16)xa1.z; a[7]=(_Float16)xa1.w;
            acc0 = __builtin_amdgcn_mfma_f32_16x16x32_f16(a, wfrag(wv,0), acc0, 0,0,0);
            acc1 = __builtin_amdgcn_mfma_f32_16x16x32_f16(a, wfrag(wv,1), acc1, 0,0,0);
        }
        // [B] h(t-32) part (prefetched regs)
        if (t >= 32) {
            acc0 = __builtin_amdgcn_mfma_f32_16x16x32_f16(h32a, wfrag(c32a,0), acc0, 0,0,0);
            acc1 = __builtin_amdgcn_mfma_f32_16x16x32_f16(h32a, wfrag(c32a,1), acc1, 0,0,0);
            acc0 = __builtin_amdgcn_mfma_f32_16x16x32_f16(h32b, wfrag(c32b,0), acc0, 0,0,0);
            acc1 = __builtin_amdgcn_mfma_f32_16x16x32_f16(h32b, wfrag(c32b,1), acc1, 0,0,0);
        }
        // [C] h(t-1): fused dual-chunk tagged wait + 4 MFMAs
        if (t > 0) {
            const int sP = (t - 1) & 63;
            const unsigned p1 = ((t - 1) >> 6) & 1;
            half8 ha, hb;
            loadfrag2x(sP, c1a - 22, c1b - 22, p1, ha, hb);
            acc0 = __builtin_amdgcn_mfma_f32_16x16x32_f16(ha, wfrag(c1a,0), acc0, 0,0,0);
            acc1 = __builtin_amdgcn_mfma_f32_16x16x32_f16(ha, wfrag(c1a,1), acc1, 0,0,0);
            acc0 = __builtin_amdgcn_mfma_f32_16x16x32_f16(hb, wfrag(c1b,0), acc0, 0,0,0);
            acc1 = __builtin_amdgcn_mfma_f32_16x16x32_f16(hb, wfrag(c1b,1), acc1, 0,0,0);
        }

        // [Px] x prefetch for t+1 (plain loads; flight window = [D]+[E]+[F])
        const int tn = t + 1;
        if (tn < T_ && wv < 6) {
            const int yn = tn >> 5, xcn = tn & 31;
            const int k0 = wv * 32 + l4 * 8;
            const float* xs = x + ((size_t)(gb * 3 + (k0 >> 6)) * 256
                                   + yn * 8 + ((k0 >> 3) & 7)) * 256 + xcn * 8;
            xa0 = ((const float4*)xs)[0];
            xa1 = ((const float4*)xs)[1];
        }

        // [D] partials -> LDS (parity double-buffer)
        {
            float* Pw = Psm + (size_t)((par * 8 + wv) * 16) * 33;
#pragma unroll
            for (int r = 0; r < 4; ++r) {
                Pw[(l4 * 4 + r) * 33 + l15]      = acc0[r];
                Pw[(l4 * 4 + r) * 33 + 16 + l15] = acc1[r];
            }
        }
        __syncthreads();   // [E] the only barrier per step

        // [F] pointwise + packed 16B publish (waves 0-1); waves 2-7 run ahead
        if (tid < 128) {
            float gi = bI, gf = bF, gg = bG, go = bO;
#pragma unroll
            for (int q = 0; q < 8; ++q) {
                const float* Pq = Psm + ((size_t)((par * 8 + q) * 16 + pb)) * 33 + pc * 4;
                gi += Pq[0]; gf += Pq[1]; gg += Pq[2]; go += Pq[3];
            }
            const float cprev = cst[tid];
            const float si = 1.f / (1.f + __expf(-gi));
            const float sf = 1.f / (1.f + __expf(-gf));
            const float so = 1.f / (1.f + __expf(-go));
            const float tg = 2.f / (1.f + __expf(-2.f * gg)) - 1.f;
            const float cn = sf * cprev + si * tg;
            const float th = 2.f / (1.f + __expf(-2.f * cn)) - 1.f;
            const float hn = so * th;
            cst[tid] = cn;

            union { _Float16 f; unsigned short s; } cv; cv.f = (_Float16)hn;
            unsigned hb16 = ((unsigned)cv.s & ~1u) | (unsigned)((t >> 6) & 1);  // force tag
            unsigned other = (unsigned)__shfl_xor((int)hb16, 1);
            unsigned pairv = (pc & 1) ? ((other & 0xffffu) | (hb16 << 16))
                                      : ((hb16 & 0xffffu) | (other << 16));
            unsigned hi  = (unsigned)__shfl_xor((int)pairv, 2);
            unsigned pv4 = (unsigned)__shfl_xor((int)pairv, 4);
            unsigned hi4 = (unsigned)__shfl_xor((int)hi, 4);
            if (pc == 0) {
                u32x4 val;
                val[0] = pairv; val[1] = hi;     // u64 for ch 0..3 (this quad)
                val[2] = pv4;   val[3] = hi4;    // u64 for ch 4..7 (from pc==4)
                // fragment-major publish: u64 idx = block + w*32 + pb*2
                const u64* dst = ring + ((size_t)((t & 63) * 4 + g)) * 2048
                               + (size_t)w * 32 + (size_t)pb * 2;
                asm volatile("global_store_dwordx4 %0, %1, off sc0 sc1"
                             :: "v"(dst), "v"(val) : "memory");
            }
            out[(size_t)(g * 16 + pb) * (T_ * 512) + (size_t)t * 512 + gc] = hn;
        }

        // [G/H] h(t+1-32) prefetch: fused 16B loads (31 steps old, no stall)
        if (tn < T_ && tn >= 32) {
            const int sO = (tn - 32) & 63;
            const unsigned p32 = ((tn - 32) >> 6) & 1;
            loadfrag2x(sO, c32a - 6, c32b - 6, p32, h32a, h32b);
        }
    }
}

extern "C" void kernel_launch(void* const* d_in, const int* in_sizes, int n_in,
                              void* d_out, int out_size, void* d_ws, size_t ws_size,
                              hipStream_t stream) {
    const float* x   = (const float*)d_in[0];
    const float* Wih = (const float*)d_in[1];
    const float* Whh = (const float*)d_in[2];
    const float* bih = (const float*)d_in[3];
    const float* bhh = (const float*)d_in[4];
    float* out = (float*)d_out;

    u64* ring = (u64*)d_ws;   // 64*4*2048 u64 = 4 MB

    // LSB pattern 1 everywhere != gen-0 parity 0
    hipMemsetAsync(ring, 0x01, 64ull * 4 * 2048 * 8, stream);

    (void)hipFuncSetAttribute((const void*)lstm_persist,
                              hipFuncAttributeMaxDynamicSharedMemorySize, LDS_ALL);

    hipLaunchKernelGGL(lstm_persist, dim3(256), dim3(512), LDS_ALL, stream,
                       x, Wih, Whh, bih, bhh, out, ring);
}